// Round 1
// baseline (270.891 us; speedup 1.0000x reference)
//
#include <hip/hip_runtime.h>

#define NN 256
#define CC 16
#define OO 16
#define BB 16
#define NTILE 16
#define NPAIRS 136   // NTILE*(NTILE+1)/2

// workspace layout (float offsets)
#define OFF_DIAG 0         // B*C*N*2 = 131072
#define OFF_COL  131072
#define OFF_ROW  262144
#define OFF_TOT  393216    // B*C*2 = 512
#define OFF_DSUM 393728    // 512
#define OFF_W13  394240    // 256
#define OFF_RI   394496    // B*O*N*2 = 131072
#define OFF_CJ   525568
#define OFF_DM   656640
#define OFF_S0   787712    // 512
// total 788224 floats = ~3.0 MiB

// ---------------------------------------------------------------------------
// Kernel 1: per-(b,c) reductions: diag, col_sum (over i), row_sum (over j),
// total sum, diag sum. One 1024-thread block per (b,c) slice (512 KiB).
// ---------------------------------------------------------------------------
__global__ __launch_bounds__(1024) void k_reduce(const float* __restrict__ in,
                                                 const float* __restrict__ w,
                                                 float* __restrict__ ws) {
    float* diagA = ws + OFF_DIAG;
    float* colA  = ws + OFF_COL;
    float* rowA  = ws + OFF_ROW;
    float* totA  = ws + OFF_TOT;
    float* dsumA = ws + OFF_DSUM;
    float* w13p  = ws + OFF_W13;

    const int bc  = blockIdx.x;            // b*C + c
    const int tid = threadIdx.x;
    const int wv  = tid >> 6;              // wave 0..15
    const int ln  = tid & 63;

    if (bc == 0 && tid < 256) {
        int c = tid >> 4, o = tid & 15;
        w13p[c * 16 + o] = w[(c * OO + o) * 15 + 13];
    }

    const float* base = in + (size_t)bc * (NN * NN * 2);

    __shared__ float colLDS[16][512];
    __shared__ float rowLDS[512];
    __shared__ float diagLDS[512];
    __shared__ float redT[16][2];
    __shared__ float redD[16][2];

    float c0x = 0, c0y = 0, c1x = 0, c1y = 0;
    float c2x = 0, c2y = 0, c3x = 0, c3y = 0;
    float dsx = 0, dsy = 0;

    for (int i = wv; i < NN; i += 16) {
        const float2* rowp = (const float2*)(base + i * (NN * 2));
        float2 v0 = rowp[ln];
        float2 v1 = rowp[64 + ln];
        float2 v2 = rowp[128 + ln];
        float2 v3 = rowp[192 + ln];
        c0x += v0.x; c0y += v0.y;
        c1x += v1.x; c1y += v1.y;
        c2x += v2.x; c2y += v2.y;
        c3x += v3.x; c3y += v3.y;
        float sx = v0.x + v1.x + v2.x + v3.x;
        float sy = v0.y + v1.y + v2.y + v3.y;
#pragma unroll
        for (int off = 32; off >= 1; off >>= 1) {
            sx += __shfl_xor(sx, off);
            sy += __shfl_xor(sy, off);
        }
        if (ln == 0) { rowLDS[i * 2] = sx; rowLDS[i * 2 + 1] = sy; }
        int jj = i >> 6;
        if (ln == (i & 63)) {
            float2 dv = (jj == 0) ? v0 : (jj == 1) ? v1 : (jj == 2) ? v2 : v3;
            diagLDS[i * 2] = dv.x; diagLDS[i * 2 + 1] = dv.y;
            dsx += dv.x; dsy += dv.y;
        }
    }
    // col partial sums: wave wv covers cols jj*64+ln
    colLDS[wv][ln * 2]           = c0x; colLDS[wv][ln * 2 + 1]       = c0y;
    colLDS[wv][128 + ln * 2]     = c1x; colLDS[wv][128 + ln * 2 + 1] = c1y;
    colLDS[wv][256 + ln * 2]     = c2x; colLDS[wv][256 + ln * 2 + 1] = c2y;
    colLDS[wv][384 + ln * 2]     = c3x; colLDS[wv][384 + ln * 2 + 1] = c3y;

    // diag sum: reduce across all threads
#pragma unroll
    for (int off = 32; off >= 1; off >>= 1) {
        dsx += __shfl_xor(dsx, off);
        dsy += __shfl_xor(dsy, off);
    }
    if (ln == 0) { redD[wv][0] = dsx; redD[wv][1] = dsy; }
    __syncthreads();

    float totpart = 0.f;
    if (tid < 512) {
        float s = 0.f;
#pragma unroll
        for (int w2 = 0; w2 < 16; w2++) s += colLDS[w2][tid];
        colA[bc * 512 + tid]  = s;
        rowA[bc * 512 + tid]  = rowLDS[tid];
        diagA[bc * 512 + tid] = diagLDS[tid];
        totpart = s;
    }
    // total sum: reduce preserving k-parity (tid&1), waves 8..15 contribute 0
#pragma unroll
    for (int off = 32; off >= 2; off >>= 1) totpart += __shfl_xor(totpart, off);
    if (ln < 2) redT[wv][ln] = totpart;
    __syncthreads();
    if (tid == 0) {
        float t0 = 0, t1 = 0, d0 = 0, d1 = 0;
        for (int w2 = 0; w2 < 16; w2++) {
            t0 += redT[w2][0]; t1 += redT[w2][1];
            d0 += redD[w2][0]; d1 += redD[w2][1];
        }
        totA[bc * 2]  = t0; totA[bc * 2 + 1]  = t1;
        dsumA[bc * 2] = d0; dsumA[bc * 2 + 1] = d1;
    }
}

// ---------------------------------------------------------------------------
// Kernel 2: build broadcast terms Ri, Cj, Dm (B,O,N,2) and S0 (B,O,2).
// One 256-thread block per (b,o); thread = position m.
// ---------------------------------------------------------------------------
__global__ __launch_bounds__(256) void k_terms(const float* __restrict__ w,
                                               float* __restrict__ ws) {
    const float* diagA = ws + OFF_DIAG;
    const float* colA  = ws + OFF_COL;
    const float* rowA  = ws + OFF_ROW;
    const float* totA  = ws + OFF_TOT;
    const float* dsumA = ws + OFF_DSUM;
    float* RiA = ws + OFF_RI;
    float* CjA = ws + OFF_CJ;
    float* DmA = ws + OFF_DM;
    float* S0A = ws + OFF_S0;

    const int b = blockIdx.x >> 4;
    const int o = blockIdx.x & 15;
    const int m = threadIdx.x;

    __shared__ float wL[CC][15];
    if (m < CC * 15) wL[m / 15][m % 15] = w[(m / 15) * (OO * 15) + o * 15 + m % 15];
    __syncthreads();

    float rix = 0, riy = 0, cjx = 0, cjy = 0, dmx = 0, dmy = 0;
    float s0x = 0, s0y = 0, dcx = 0, dcy = 0;
#pragma unroll
    for (int c = 0; c < CC; c++) {
        int bcm = (b * CC + c) * NN + m;
        float2 dg = ((const float2*)diagA)[bcm];
        float2 cs = ((const float2*)colA)[bcm];
        float2 rs = ((const float2*)rowA)[bcm];
        float w4 = wL[c][4], w5 = wL[c][5], w6 = wL[c][6];
        float w7 = wL[c][7], w8 = wL[c][8], w9 = wL[c][9];
        float wa = wL[c][10], wb = wL[c][11], wc = wL[c][12];
        rix += w6 * dg.x + w9 * cs.x + wc * rs.x;
        riy += w6 * dg.y + w9 * cs.y + wc * rs.y;
        cjx += w5 * dg.x + w8 * cs.x + wb * rs.x;
        cjy += w5 * dg.y + w8 * cs.y + wb * rs.y;
        dmx += w4 * dg.x + w7 * cs.x + wa * rs.x;
        dmy += w4 * dg.y + w7 * cs.y + wa * rs.y;
        float2 tt = ((const float2*)totA)[b * CC + c];
        float2 dd = ((const float2*)dsumA)[b * CC + c];
        float vx = dd.x * (1.0f / NN) + tt.x;
        float vy = dd.y * (1.0f / NN) + tt.y;
        s0x += wL[c][0] * vx; s0y += wL[c][0] * vy;
        dcx += wL[c][1] * vx; dcy += wL[c][1] * vy;
    }
    int om = (b * OO + o) * NN + m;
    ((float2*)RiA)[om] = make_float2(rix, riy);
    ((float2*)CjA)[om] = make_float2(cjx, cjy);
    ((float2*)DmA)[om] = make_float2(dmx + dcx, dmy + dcy);
    if (m == 0) ((float2*)S0A)[b * OO + o] = make_float2(s0x, s0y);
}

// ---------------------------------------------------------------------------
// Kernel 3: main pass. One block per (b, tile-pair (I,J), I<=J).
// Thread (ti,tj) accumulates P[o]=sum_c w13*A, Q[o]=sum_c w13*B in registers,
// then XOR-swizzled LDS exchange gives the transposed partners so
// out1 = P + Q^T (tile I,J) and out2 = Q + P^T (tile J,I).
// ---------------------------------------------------------------------------
__global__ __launch_bounds__(256) void k_main(const float* __restrict__ in,
                                              float* __restrict__ out,
                                              const float* __restrict__ ws) {
    const float* RiA  = ws + OFF_RI;
    const float* CjA  = ws + OFF_CJ;
    const float* DmA  = ws + OFF_DM;
    const float* S0A  = ws + OFF_S0;
    const float* w13p = ws + OFF_W13;

    const int b = blockIdx.x / NPAIRS;
    int p = blockIdx.x % NPAIRS;
    int I = 0;
    { int cnt = NTILE; while (p >= cnt) { p -= cnt; cnt--; I++; } }
    const int J = I + p;

    const int tid = threadIdx.x;
    const int ti = tid >> 4;
    const int tj = tid & 15;

    __shared__ float  xch[256 * 34];      // 34-float stride: conflict-free b64 xpose
    __shared__ float2 RiL[16][16];        // [o][pos]
    __shared__ float2 CjL[16][16];

    {   // preload Ri @ I-rows, Cj @ J-cols (o = tid>>4, ii = tid&15)
        RiL[ti][tj] = ((const float2*)RiA)[(b * OO + ti) * NN + I * 16 + tj];
        CjL[ti][tj] = ((const float2*)CjA)[(b * OO + ti) * NN + J * 16 + tj];
    }
    __syncthreads();

    float2 P[16], Q[16];
#pragma unroll
    for (int o = 0; o < 16; o++) { P[o] = make_float2(0.f, 0.f); Q[o] = make_float2(0.f, 0.f); }

    const float2* pA = (const float2*)in + ((b * CC) * NN + I * 16 + ti) * NN + J * 16 + tj;
    const float2* pB = (const float2*)in + ((b * CC) * NN + J * 16 + ti) * NN + I * 16 + tj;

#pragma unroll 4
    for (int c = 0; c < CC; c++) {
        float2 a  = pA[c * (NN * NN)];
        float2 bb = pB[c * (NN * NN)];
#pragma unroll
        for (int o = 0; o < 16; o++) {
            float wv = w13p[c * 16 + o];   // uniform -> scalar load
            P[o].x += wv * a.x;  P[o].y += wv * a.y;
            Q[o].x += wv * bb.x; Q[o].y += wv * bb.y;
        }
    }

    const int sidx = ti * 16 + (tj ^ ti);   // own slot
    const int ridx = tj * 16 + (ti ^ tj);   // partner (tj,ti)'s slot
    const bool dgl = (I == J) && (ti == tj);

    // ---- phase 1: exchange Q, store out1 (tile I,J) ----
#pragma unroll
    for (int o = 0; o < 16; o++) *(float2*)&xch[sidx * 34 + o * 2] = Q[o];
    __syncthreads();
    float2 Qt[16];
#pragma unroll
    for (int o = 0; o < 16; o++) Qt[o] = *(const float2*)&xch[ridx * 34 + o * 2];
    {
        const int gi = I * 16 + ti, gj = J * 16 + tj;
#pragma unroll
        for (int o = 0; o < 16; o++) {
            float2 s0 = ((const float2*)S0A)[b * OO + o];
            float2 ri = RiL[o][ti];
            float2 cj = CjL[o][tj];
            float vx = P[o].x + Qt[o].x + s0.x + ri.x + cj.x;
            float vy = P[o].y + Qt[o].y + s0.y + ri.y + cj.y;
            if (dgl) {
                float2 dm = ((const float2*)DmA)[(b * OO + o) * NN + gi];
                vx += dm.x; vy += dm.y;
            }
            ((float2*)out)[((b * OO + o) * NN + gi) * NN + gj] = make_float2(vx, vy);
        }
    }
    __syncthreads();   // xch + RiL/CjL reads complete before overwrite

    // ---- phase 2: exchange P, reload terms for tile (J,I), store out2 ----
#pragma unroll
    for (int o = 0; o < 16; o++) *(float2*)&xch[sidx * 34 + o * 2] = P[o];
    {
        RiL[ti][tj] = ((const float2*)RiA)[(b * OO + ti) * NN + J * 16 + tj];
        CjL[ti][tj] = ((const float2*)CjA)[(b * OO + ti) * NN + I * 16 + tj];
    }
    __syncthreads();
    float2 Pt[16];
#pragma unroll
    for (int o = 0; o < 16; o++) Pt[o] = *(const float2*)&xch[ridx * 34 + o * 2];
    {
        const int gi = J * 16 + ti, gj = I * 16 + tj;
#pragma unroll
        for (int o = 0; o < 16; o++) {
            float2 s0 = ((const float2*)S0A)[b * OO + o];
            float2 ri = RiL[o][ti];
            float2 cj = CjL[o][tj];
            float vx = Q[o].x + Pt[o].x + s0.x + ri.x + cj.x;
            float vy = Q[o].y + Pt[o].y + s0.y + ri.y + cj.y;
            if (dgl) {
                float2 dm = ((const float2*)DmA)[(b * OO + o) * NN + gi];
                vx += dm.x; vy += dm.y;
            }
            ((float2*)out)[((b * OO + o) * NN + gi) * NN + gj] = make_float2(vx, vy);
        }
    }
}

extern "C" void kernel_launch(void* const* d_in, const int* in_sizes, int n_in,
                              void* d_out, int out_size, void* d_ws, size_t ws_size,
                              hipStream_t stream) {
    const float* in = (const float*)d_in[0];
    const float* w  = (const float*)d_in[1];
    float* out = (float*)d_out;
    float* ws  = (float*)d_ws;

    hipLaunchKernelGGL(k_reduce, dim3(BB * CC), dim3(1024), 0, stream, in, w, ws);
    hipLaunchKernelGGL(k_terms,  dim3(BB * OO), dim3(256),  0, stream, w, ws);
    hipLaunchKernelGGL(k_main,   dim3(BB * NPAIRS), dim3(256), 0, stream, in, out, ws);
}

// Round 2
// 270.406 us; speedup vs baseline: 1.0018x; 1.0018x over previous
//
#include <hip/hip_runtime.h>

#define NN 256
#define CC 16
#define OO 16
#define BB 16
#define NTILE 16
#define NPAIRS 136   // NTILE*(NTILE+1)/2

// workspace layout (float offsets)
#define OFF_DIAG 0         // B*C*N*2 = 131072
#define OFF_COL  131072
#define OFF_ROW  262144
#define OFF_TOT  393216    // B*C*2 = 512
#define OFF_DSUM 393728    // 512
#define OFF_RI   394496    // B*O*N*2 = 131072
#define OFF_CJ   525568
#define OFF_DM   656640
#define OFF_S0   787712    // 512

// ---------------------------------------------------------------------------
// Kernel 1: per-(b,c) reductions: diag, col_sum (over i), row_sum (over j),
// total sum, diag sum. One 1024-thread block per (b,c) slice (512 KiB).
// float4 loads: 16 B/lane, 2 loads per row per wave.
// ---------------------------------------------------------------------------
__global__ __launch_bounds__(1024) void k_reduce(const float* __restrict__ in,
                                                 float* __restrict__ ws) {
    float* diagA = ws + OFF_DIAG;
    float* colA  = ws + OFF_COL;
    float* rowA  = ws + OFF_ROW;
    float* totA  = ws + OFF_TOT;
    float* dsumA = ws + OFF_DSUM;

    const int bc  = blockIdx.x;            // b*C + c
    const int tid = threadIdx.x;
    const int wv  = tid >> 6;              // wave 0..15
    const int ln  = tid & 63;

    const float* base = in + (size_t)bc * (NN * NN * 2);

    __shared__ float colLDS[16][512];
    __shared__ float rowLDS[512];
    __shared__ float diagLDS[512];
    __shared__ float redT[16][2];
    __shared__ float redD[16][2];

    // col accumulators: v0 covers float cols 4ln..4ln+3, v1 covers 256+4ln..+3
    float a0 = 0, a1 = 0, a2 = 0, a3 = 0;
    float b0 = 0, b1 = 0, b2 = 0, b3 = 0;
    float dsx = 0, dsy = 0;

    for (int i = wv; i < NN; i += 16) {
        const float4* rowp = (const float4*)(base + i * (NN * 2));
        float4 v0 = rowp[ln];
        float4 v1 = rowp[64 + ln];
        a0 += v0.x; a1 += v0.y; a2 += v0.z; a3 += v0.w;
        b0 += v1.x; b1 += v1.y; b2 += v1.z; b3 += v1.w;
        float sx = v0.x + v0.z + v1.x + v1.z;
        float sy = v0.y + v0.w + v1.y + v1.w;
#pragma unroll
        for (int off = 32; off >= 1; off >>= 1) {
            sx += __shfl_xor(sx, off);
            sy += __shfl_xor(sy, off);
        }
        if (ln == 0) { rowLDS[i * 2] = sx; rowLDS[i * 2 + 1] = sy; }
        // diag element of row i lives at float4 index k4 = i>>1, elem pair (i&1)
        int k4 = i >> 1;
        if (ln == (k4 & 63)) {
            float4 dv = (k4 >> 6) ? v1 : v0;
            float dx = (i & 1) ? dv.z : dv.x;
            float dy = (i & 1) ? dv.w : dv.y;
            diagLDS[i * 2] = dx; diagLDS[i * 2 + 1] = dy;
            dsx += dx; dsy += dy;
        }
    }
    // col partial sums
    colLDS[wv][4 * ln]       = a0; colLDS[wv][4 * ln + 1]       = a1;
    colLDS[wv][4 * ln + 2]   = a2; colLDS[wv][4 * ln + 3]       = a3;
    colLDS[wv][256 + 4 * ln]     = b0; colLDS[wv][256 + 4 * ln + 1] = b1;
    colLDS[wv][256 + 4 * ln + 2] = b2; colLDS[wv][256 + 4 * ln + 3] = b3;

    // diag sum: reduce across all threads
#pragma unroll
    for (int off = 32; off >= 1; off >>= 1) {
        dsx += __shfl_xor(dsx, off);
        dsy += __shfl_xor(dsy, off);
    }
    if (ln == 0) { redD[wv][0] = dsx; redD[wv][1] = dsy; }
    __syncthreads();

    float totpart = 0.f;
    if (tid < 512) {
        float s = 0.f;
#pragma unroll
        for (int w2 = 0; w2 < 16; w2++) s += colLDS[w2][tid];
        colA[bc * 512 + tid]  = s;
        rowA[bc * 512 + tid]  = rowLDS[tid];
        diagA[bc * 512 + tid] = diagLDS[tid];
        totpart = s;
    }
    // total sum: reduce preserving k-parity (tid&1); waves 8..15 contribute 0
#pragma unroll
    for (int off = 32; off >= 2; off >>= 1) totpart += __shfl_xor(totpart, off);
    if (ln < 2) redT[wv][ln] = totpart;
    __syncthreads();
    if (tid == 0) {
        float t0 = 0, t1 = 0, d0 = 0, d1 = 0;
        for (int w2 = 0; w2 < 16; w2++) {
            t0 += redT[w2][0]; t1 += redT[w2][1];
            d0 += redD[w2][0]; d1 += redD[w2][1];
        }
        totA[bc * 2]  = t0; totA[bc * 2 + 1]  = t1;
        dsumA[bc * 2] = d0; dsumA[bc * 2 + 1] = d1;
    }
}

// ---------------------------------------------------------------------------
// Kernel 2: build broadcast terms Ri, Cj, Dm (B,O,N,2) and S0 (B,O,2).
// One 256-thread block per (b,o); thread = position m.
// ---------------------------------------------------------------------------
__global__ __launch_bounds__(256) void k_terms(const float* __restrict__ w,
                                               float* __restrict__ ws) {
    const float* diagA = ws + OFF_DIAG;
    const float* colA  = ws + OFF_COL;
    const float* rowA  = ws + OFF_ROW;
    const float* totA  = ws + OFF_TOT;
    const float* dsumA = ws + OFF_DSUM;
    float* RiA = ws + OFF_RI;
    float* CjA = ws + OFF_CJ;
    float* DmA = ws + OFF_DM;
    float* S0A = ws + OFF_S0;

    const int b = blockIdx.x >> 4;
    const int o = blockIdx.x & 15;
    const int m = threadIdx.x;

    __shared__ float wL[CC][15];
    if (m < CC * 15) wL[m / 15][m % 15] = w[(m / 15) * (OO * 15) + o * 15 + m % 15];
    __syncthreads();

    float rix = 0, riy = 0, cjx = 0, cjy = 0, dmx = 0, dmy = 0;
    float s0x = 0, s0y = 0, dcx = 0, dcy = 0;
#pragma unroll
    for (int c = 0; c < CC; c++) {
        int bcm = (b * CC + c) * NN + m;
        float2 dg = ((const float2*)diagA)[bcm];
        float2 cs = ((const float2*)colA)[bcm];
        float2 rs = ((const float2*)rowA)[bcm];
        float w4 = wL[c][4], w5 = wL[c][5], w6 = wL[c][6];
        float w7 = wL[c][7], w8 = wL[c][8], w9 = wL[c][9];
        float wa = wL[c][10], wb = wL[c][11], wc = wL[c][12];
        rix += w6 * dg.x + w9 * cs.x + wc * rs.x;
        riy += w6 * dg.y + w9 * cs.y + wc * rs.y;
        cjx += w5 * dg.x + w8 * cs.x + wb * rs.x;
        cjy += w5 * dg.y + w8 * cs.y + wb * rs.y;
        dmx += w4 * dg.x + w7 * cs.x + wa * rs.x;
        dmy += w4 * dg.y + w7 * cs.y + wa * rs.y;
        float2 tt = ((const float2*)totA)[b * CC + c];
        float2 dd = ((const float2*)dsumA)[b * CC + c];
        float vx = dd.x * (1.0f / NN) + tt.x;
        float vy = dd.y * (1.0f / NN) + tt.y;
        s0x += wL[c][0] * vx; s0y += wL[c][0] * vy;
        dcx += wL[c][1] * vx; dcy += wL[c][1] * vy;
    }
    int om = (b * OO + o) * NN + m;
    ((float2*)RiA)[om] = make_float2(rix, riy);
    ((float2*)CjA)[om] = make_float2(cjx, cjy);
    ((float2*)DmA)[om] = make_float2(dmx + dcx, dmy + dcy);
    if (m == 0) ((float2*)S0A)[b * OO + o] = make_float2(s0x, s0y);
}

// ---------------------------------------------------------------------------
// Kernel 3: main pass. One block per (b, tile-pair (I,J), I<=J).
// All broadcast data (w13, S0, Ri/Cj for both tiles) staged in LDS upfront.
// Thread (ti,tj) accumulates P[o]=sum_c w13*A, Q[o]=sum_c w13*B in registers,
// XOR-swizzled LDS exchange produces transposed partners:
//   out(I,J) = P + Q^T, out(J,I) = Q + P^T.  Phase 2 skipped when I==J (P==Q).
// ---------------------------------------------------------------------------
__global__ __launch_bounds__(256) void k_main(const float* __restrict__ in,
                                              const float* __restrict__ w,
                                              float* __restrict__ out,
                                              const float* __restrict__ ws) {
    const float* RiA  = ws + OFF_RI;
    const float* CjA  = ws + OFF_CJ;
    const float* DmA  = ws + OFF_DM;
    const float* S0A  = ws + OFF_S0;

    const int b = blockIdx.x / NPAIRS;
    int p = blockIdx.x % NPAIRS;
    int I = 0;
    { int cnt = NTILE; while (p >= cnt) { p -= cnt; cnt--; I++; } }
    const int J = I + p;

    const int tid = threadIdx.x;
    const int ti = tid >> 4;
    const int tj = tid & 15;

    __shared__ float  xch[256 * 34];      // 34-float stride transpose buffer
    __shared__ float  wsm[256];           // w13 [c][o]
    __shared__ float2 s0L[16];
    __shared__ float2 RiI[16][16];        // Ri at rows of tile I   [o][pos]
    __shared__ float2 CjJ[16][16];        // Cj at cols of tile J
    __shared__ float2 RiJ[16][16];        // Ri at rows of tile J (phase 2)
    __shared__ float2 CjI[16][16];        // Cj at cols of tile I (phase 2)

    {   // stage everything block-wide once
        wsm[tid] = w[tid * 15 + 13];      // tid = c*16+o  ->  w[(c*16+o)*15+13]
        RiI[ti][tj] = ((const float2*)RiA)[(b * OO + ti) * NN + I * 16 + tj];
        CjJ[ti][tj] = ((const float2*)CjA)[(b * OO + ti) * NN + J * 16 + tj];
        if (I != J) {
            RiJ[ti][tj] = ((const float2*)RiA)[(b * OO + ti) * NN + J * 16 + tj];
            CjI[ti][tj] = ((const float2*)CjA)[(b * OO + ti) * NN + I * 16 + tj];
        }
        if (tid < 16) s0L[tid] = ((const float2*)S0A)[b * OO + tid];
    }
    __syncthreads();

    float2 P[16], Q[16];
#pragma unroll
    for (int o = 0; o < 16; o++) { P[o] = make_float2(0.f, 0.f); Q[o] = make_float2(0.f, 0.f); }

    const float2* pA = (const float2*)in + ((b * CC) * NN + I * 16 + ti) * NN + J * 16 + tj;
    const float2* pB = (const float2*)in + ((b * CC) * NN + J * 16 + ti) * NN + I * 16 + tj;

#pragma unroll 8
    for (int c = 0; c < CC; c++) {
        float2 a  = pA[c * (NN * NN)];
        float2 bb = pB[c * (NN * NN)];
#pragma unroll
        for (int o = 0; o < 16; o++) {
            float wv = wsm[c * 16 + o];   // LDS broadcast
            P[o].x += wv * a.x;  P[o].y += wv * a.y;
            Q[o].x += wv * bb.x; Q[o].y += wv * bb.y;
        }
    }

    const int sidx = ti * 16 + (tj ^ ti);   // own slot
    const int ridx = tj * 16 + (ti ^ tj);   // partner (tj,ti)'s slot
    const bool dgl = (I == J) && (ti == tj);

    // ---- phase 1: exchange Q, store out(I,J) = P + Q^T + terms ----
#pragma unroll
    for (int o = 0; o < 16; o++) *(float2*)&xch[sidx * 34 + o * 2] = Q[o];
    __syncthreads();
    {
        const int gi = I * 16 + ti, gj = J * 16 + tj;
#pragma unroll
        for (int o = 0; o < 16; o++) {
            float2 qt = *(const float2*)&xch[ridx * 34 + o * 2];
            float2 s0 = s0L[o];
            float2 ri = RiI[o][ti];
            float2 cj = CjJ[o][tj];
            float vx = P[o].x + qt.x + s0.x + ri.x + cj.x;
            float vy = P[o].y + qt.y + s0.y + ri.y + cj.y;
            if (dgl) {
                float2 dm = ((const float2*)DmA)[(b * OO + o) * NN + gi];
                vx += dm.x; vy += dm.y;
            }
            ((float2*)out)[((b * OO + o) * NN + gi) * NN + gj] = make_float2(vx, vy);
        }
    }

    if (I == J) return;   // P==Q there: tile (J,I) identical, already written

    __syncthreads();   // xch reads complete before overwrite

    // ---- phase 2: exchange P, store out(J,I) = Q + P^T + terms ----
#pragma unroll
    for (int o = 0; o < 16; o++) *(float2*)&xch[sidx * 34 + o * 2] = P[o];
    __syncthreads();
    {
        const int gi = J * 16 + ti, gj = I * 16 + tj;
#pragma unroll
        for (int o = 0; o < 16; o++) {
            float2 pt = *(const float2*)&xch[ridx * 34 + o * 2];
            float2 s0 = s0L[o];
            float2 ri = RiJ[o][ti];
            float2 cj = CjI[o][tj];
            float vx = Q[o].x + pt.x + s0.x + ri.x + cj.x;
            float vy = Q[o].y + pt.y + s0.y + ri.y + cj.y;
            ((float2*)out)[((b * OO + o) * NN + gi) * NN + gj] = make_float2(vx, vy);
        }
    }
}

extern "C" void kernel_launch(void* const* d_in, const int* in_sizes, int n_in,
                              void* d_out, int out_size, void* d_ws, size_t ws_size,
                              hipStream_t stream) {
    const float* in = (const float*)d_in[0];
    const float* w  = (const float*)d_in[1];
    float* out = (float*)d_out;
    float* ws  = (float*)d_ws;

    hipLaunchKernelGGL(k_reduce, dim3(BB * CC), dim3(1024), 0, stream, in, ws);
    hipLaunchKernelGGL(k_terms,  dim3(BB * OO), dim3(256),  0, stream, w, ws);
    hipLaunchKernelGGL(k_main,   dim3(BB * NPAIRS), dim3(256), 0, stream, in, w, out, ws);
}

// Round 3
// 265.709 us; speedup vs baseline: 1.0195x; 1.0177x over previous
//
#include <hip/hip_runtime.h>

#define NN 256
#define CC 16
#define OO 16
#define BB 16
#define NTILE 16
#define NPAIRS 136   // NTILE*(NTILE+1)/2

// workspace layout (float offsets)
#define OFF_DIAG 0         // B*C*N*2 = 131072
#define OFF_COL  131072
#define OFF_ROW  262144
#define OFF_TOT  393216    // B*C*2 = 512
#define OFF_DSUM 393728    // 512
#define OFF_RI   394496    // B*O*N*2 = 131072
#define OFF_CJ   525568
#define OFF_DM   656640
#define OFF_S0   787712    // 512

// nontemporal float2 helpers (bit-exact via double reinterpret)
__device__ __forceinline__ float2 nt_load2(const float2* p) {
    double d = __builtin_nontemporal_load((const double*)p);
    float2 r; *(double*)&r = d; return r;
}
__device__ __forceinline__ void nt_store2(float2* p, float2 v) {
    double d; *(float2*)&d = v;
    __builtin_nontemporal_store(d, (double*)p);
}

// ---------------------------------------------------------------------------
// Kernel 1: per-(b,c) reductions: diag, col_sum (over i), row_sum (over j),
// total sum, diag sum. One 1024-thread block per (b,c) slice (512 KiB).
// Normal (caching) loads on purpose: this pass populates L3 for k_main.
// ---------------------------------------------------------------------------
__global__ __launch_bounds__(1024) void k_reduce(const float* __restrict__ in,
                                                 float* __restrict__ ws) {
    float* diagA = ws + OFF_DIAG;
    float* colA  = ws + OFF_COL;
    float* rowA  = ws + OFF_ROW;
    float* totA  = ws + OFF_TOT;
    float* dsumA = ws + OFF_DSUM;

    const int bc  = blockIdx.x;            // b*C + c
    const int tid = threadIdx.x;
    const int wv  = tid >> 6;              // wave 0..15
    const int ln  = tid & 63;

    const float* base = in + (size_t)bc * (NN * NN * 2);

    __shared__ float colLDS[16][512];
    __shared__ float rowLDS[512];
    __shared__ float diagLDS[512];
    __shared__ float redT[16][2];
    __shared__ float redD[16][2];

    float a0 = 0, a1 = 0, a2 = 0, a3 = 0;
    float b0 = 0, b1 = 0, b2 = 0, b3 = 0;
    float dsx = 0, dsy = 0;

    for (int i = wv; i < NN; i += 16) {
        const float4* rowp = (const float4*)(base + i * (NN * 2));
        float4 v0 = rowp[ln];
        float4 v1 = rowp[64 + ln];
        a0 += v0.x; a1 += v0.y; a2 += v0.z; a3 += v0.w;
        b0 += v1.x; b1 += v1.y; b2 += v1.z; b3 += v1.w;
        float sx = v0.x + v0.z + v1.x + v1.z;
        float sy = v0.y + v0.w + v1.y + v1.w;
#pragma unroll
        for (int off = 32; off >= 1; off >>= 1) {
            sx += __shfl_xor(sx, off);
            sy += __shfl_xor(sy, off);
        }
        if (ln == 0) { rowLDS[i * 2] = sx; rowLDS[i * 2 + 1] = sy; }
        int k4 = i >> 1;
        if (ln == (k4 & 63)) {
            float4 dv = (k4 >> 6) ? v1 : v0;
            float dx = (i & 1) ? dv.z : dv.x;
            float dy = (i & 1) ? dv.w : dv.y;
            diagLDS[i * 2] = dx; diagLDS[i * 2 + 1] = dy;
            dsx += dx; dsy += dy;
        }
    }
    colLDS[wv][4 * ln]       = a0; colLDS[wv][4 * ln + 1]       = a1;
    colLDS[wv][4 * ln + 2]   = a2; colLDS[wv][4 * ln + 3]       = a3;
    colLDS[wv][256 + 4 * ln]     = b0; colLDS[wv][256 + 4 * ln + 1] = b1;
    colLDS[wv][256 + 4 * ln + 2] = b2; colLDS[wv][256 + 4 * ln + 3] = b3;

#pragma unroll
    for (int off = 32; off >= 1; off >>= 1) {
        dsx += __shfl_xor(dsx, off);
        dsy += __shfl_xor(dsy, off);
    }
    if (ln == 0) { redD[wv][0] = dsx; redD[wv][1] = dsy; }
    __syncthreads();

    float totpart = 0.f;
    if (tid < 512) {
        float s = 0.f;
#pragma unroll
        for (int w2 = 0; w2 < 16; w2++) s += colLDS[w2][tid];
        colA[bc * 512 + tid]  = s;
        rowA[bc * 512 + tid]  = rowLDS[tid];
        diagA[bc * 512 + tid] = diagLDS[tid];
        totpart = s;
    }
#pragma unroll
    for (int off = 32; off >= 2; off >>= 1) totpart += __shfl_xor(totpart, off);
    if (ln < 2) redT[wv][ln] = totpart;
    __syncthreads();
    if (tid == 0) {
        float t0 = 0, t1 = 0, d0 = 0, d1 = 0;
        for (int w2 = 0; w2 < 16; w2++) {
            t0 += redT[w2][0]; t1 += redT[w2][1];
            d0 += redD[w2][0]; d1 += redD[w2][1];
        }
        totA[bc * 2]  = t0; totA[bc * 2 + 1]  = t1;
        dsumA[bc * 2] = d0; dsumA[bc * 2 + 1] = d1;
    }
}

// ---------------------------------------------------------------------------
// Kernel 2: build broadcast terms Ri, Cj, Dm (B,O,N,2) and S0 (B,O,2).
// ---------------------------------------------------------------------------
__global__ __launch_bounds__(256) void k_terms(const float* __restrict__ w,
                                               float* __restrict__ ws) {
    const float* diagA = ws + OFF_DIAG;
    const float* colA  = ws + OFF_COL;
    const float* rowA  = ws + OFF_ROW;
    const float* totA  = ws + OFF_TOT;
    const float* dsumA = ws + OFF_DSUM;
    float* RiA = ws + OFF_RI;
    float* CjA = ws + OFF_CJ;
    float* DmA = ws + OFF_DM;
    float* S0A = ws + OFF_S0;

    const int b = blockIdx.x >> 4;
    const int o = blockIdx.x & 15;
    const int m = threadIdx.x;

    __shared__ float wL[CC][15];
    if (m < CC * 15) wL[m / 15][m % 15] = w[(m / 15) * (OO * 15) + o * 15 + m % 15];
    __syncthreads();

    float rix = 0, riy = 0, cjx = 0, cjy = 0, dmx = 0, dmy = 0;
    float s0x = 0, s0y = 0, dcx = 0, dcy = 0;
#pragma unroll
    for (int c = 0; c < CC; c++) {
        int bcm = (b * CC + c) * NN + m;
        float2 dg = ((const float2*)diagA)[bcm];
        float2 cs = ((const float2*)colA)[bcm];
        float2 rs = ((const float2*)rowA)[bcm];
        float w4 = wL[c][4], w5 = wL[c][5], w6 = wL[c][6];
        float w7 = wL[c][7], w8 = wL[c][8], w9 = wL[c][9];
        float wa = wL[c][10], wb = wL[c][11], wc = wL[c][12];
        rix += w6 * dg.x + w9 * cs.x + wc * rs.x;
        riy += w6 * dg.y + w9 * cs.y + wc * rs.y;
        cjx += w5 * dg.x + w8 * cs.x + wb * rs.x;
        cjy += w5 * dg.y + w8 * cs.y + wb * rs.y;
        dmx += w4 * dg.x + w7 * cs.x + wa * rs.x;
        dmy += w4 * dg.y + w7 * cs.y + wa * rs.y;
        float2 tt = ((const float2*)totA)[b * CC + c];
        float2 dd = ((const float2*)dsumA)[b * CC + c];
        float vx = dd.x * (1.0f / NN) + tt.x;
        float vy = dd.y * (1.0f / NN) + tt.y;
        s0x += wL[c][0] * vx; s0y += wL[c][0] * vy;
        dcx += wL[c][1] * vx; dcy += wL[c][1] * vy;
    }
    int om = (b * OO + o) * NN + m;
    ((float2*)RiA)[om] = make_float2(rix, riy);
    ((float2*)CjA)[om] = make_float2(cjx, cjy);
    ((float2*)DmA)[om] = make_float2(dmx + dcx, dmy + dcy);
    if (m == 0) ((float2*)S0A)[b * OO + o] = make_float2(s0x, s0y);
}

// ---------------------------------------------------------------------------
// Kernel 3: main pass. One block per (b, tile-pair (I,J), I<=J).
// NT loads for input (last use — input stays L3-resident anyway) and
// NT stores for output (streaming; keeps output from evicting the
// L3-resident input, which otherwise forces late-tile reads back to HBM).
// ---------------------------------------------------------------------------
__global__ __launch_bounds__(256) void k_main(const float* __restrict__ in,
                                              const float* __restrict__ w,
                                              float* __restrict__ out,
                                              const float* __restrict__ ws) {
    const float* RiA  = ws + OFF_RI;
    const float* CjA  = ws + OFF_CJ;
    const float* DmA  = ws + OFF_DM;
    const float* S0A  = ws + OFF_S0;

    const int b = blockIdx.x / NPAIRS;
    int p = blockIdx.x % NPAIRS;
    int I = 0;
    { int cnt = NTILE; while (p >= cnt) { p -= cnt; cnt--; I++; } }
    const int J = I + p;

    const int tid = threadIdx.x;
    const int ti = tid >> 4;
    const int tj = tid & 15;

    __shared__ float  xch[256 * 34];
    __shared__ float  wsm[256];           // w13 [c][o]
    __shared__ float2 s0L[16];
    __shared__ float2 RiI[16][16];
    __shared__ float2 CjJ[16][16];
    __shared__ float2 RiJ[16][16];
    __shared__ float2 CjI[16][16];

    {
        wsm[tid] = w[tid * 15 + 13];
        RiI[ti][tj] = ((const float2*)RiA)[(b * OO + ti) * NN + I * 16 + tj];
        CjJ[ti][tj] = ((const float2*)CjA)[(b * OO + ti) * NN + J * 16 + tj];
        if (I != J) {
            RiJ[ti][tj] = ((const float2*)RiA)[(b * OO + ti) * NN + J * 16 + tj];
            CjI[ti][tj] = ((const float2*)CjA)[(b * OO + ti) * NN + I * 16 + tj];
        }
        if (tid < 16) s0L[tid] = ((const float2*)S0A)[b * OO + tid];
    }
    __syncthreads();

    float2 P[16], Q[16];
#pragma unroll
    for (int o = 0; o < 16; o++) { P[o] = make_float2(0.f, 0.f); Q[o] = make_float2(0.f, 0.f); }

    const float2* pA = (const float2*)in + ((b * CC) * NN + I * 16 + ti) * NN + J * 16 + tj;
    const float2* pB = (const float2*)in + ((b * CC) * NN + J * 16 + ti) * NN + I * 16 + tj;

#pragma unroll 8
    for (int c = 0; c < CC; c++) {
        float2 a  = nt_load2(&pA[c * (NN * NN)]);
        float2 bb = nt_load2(&pB[c * (NN * NN)]);
#pragma unroll
        for (int o = 0; o < 16; o++) {
            float wv = wsm[c * 16 + o];
            P[o].x += wv * a.x;  P[o].y += wv * a.y;
            Q[o].x += wv * bb.x; Q[o].y += wv * bb.y;
        }
    }

    const int sidx = ti * 16 + (tj ^ ti);
    const int ridx = tj * 16 + (ti ^ tj);
    const bool dgl = (I == J) && (ti == tj);

    // ---- phase 1: out(I,J) = P + Q^T + terms ----
#pragma unroll
    for (int o = 0; o < 16; o++) *(float2*)&xch[sidx * 34 + o * 2] = Q[o];
    __syncthreads();
    {
        const int gi = I * 16 + ti, gj = J * 16 + tj;
#pragma unroll
        for (int o = 0; o < 16; o++) {
            float2 qt = *(const float2*)&xch[ridx * 34 + o * 2];
            float2 s0 = s0L[o];
            float2 ri = RiI[o][ti];
            float2 cj = CjJ[o][tj];
            float vx = P[o].x + qt.x + s0.x + ri.x + cj.x;
            float vy = P[o].y + qt.y + s0.y + ri.y + cj.y;
            if (dgl) {
                float2 dm = ((const float2*)DmA)[(b * OO + o) * NN + gi];
                vx += dm.x; vy += dm.y;
            }
            nt_store2(((float2*)out) + ((b * OO + o) * NN + gi) * NN + gj,
                      make_float2(vx, vy));
        }
    }

    if (I == J) return;   // P==Q: tile (J,I) identical, already written

    __syncthreads();

    // ---- phase 2: out(J,I) = Q + P^T + terms ----
#pragma unroll
    for (int o = 0; o < 16; o++) *(float2*)&xch[sidx * 34 + o * 2] = P[o];
    __syncthreads();
    {
        const int gi = J * 16 + ti, gj = I * 16 + tj;
#pragma unroll
        for (int o = 0; o < 16; o++) {
            float2 pt = *(const float2*)&xch[ridx * 34 + o * 2];
            float2 s0 = s0L[o];
            float2 ri = RiJ[o][ti];
            float2 cj = CjI[o][tj];
            float vx = Q[o].x + pt.x + s0.x + ri.x + cj.x;
            float vy = Q[o].y + pt.y + s0.y + ri.y + cj.y;
            nt_store2(((float2*)out) + ((b * OO + o) * NN + gi) * NN + gj,
                      make_float2(vx, vy));
        }
    }
}

extern "C" void kernel_launch(void* const* d_in, const int* in_sizes, int n_in,
                              void* d_out, int out_size, void* d_ws, size_t ws_size,
                              hipStream_t stream) {
    const float* in = (const float*)d_in[0];
    const float* w  = (const float*)d_in[1];
    float* out = (float*)d_out;
    float* ws  = (float*)d_ws;

    hipLaunchKernelGGL(k_reduce, dim3(BB * CC), dim3(1024), 0, stream, in, ws);
    hipLaunchKernelGGL(k_terms,  dim3(BB * OO), dim3(256),  0, stream, w, ws);
    hipLaunchKernelGGL(k_main,   dim3(BB * NPAIRS), dim3(256), 0, stream, in, w, out, ws);
}